// Round 1
// baseline (482.495 us; speedup 1.0000x reference)
//
#include <hip/hip_runtime.h>
#include <hip/hip_bf16.h>
#include <stdint.h>

#define EMBED 2048
#define NHEADS 32
#define HDIM 64
#define BATCH 2
#define SEQ 2048
#define ATT_SCALE 0.125f
#define LOG2E 1.4426950408889634f

typedef __attribute__((ext_vector_type(8))) short bf16x8;
typedef __attribute__((ext_vector_type(4))) float f32x4;
typedef __attribute__((ext_vector_type(4))) unsigned short u16x4;

static __device__ __forceinline__ unsigned short f2bf(float f) {
  union { float f; uint32_t u; } v; v.f = f;
  uint32_t r = v.u + 0x7fffu + ((v.u >> 16) & 1u);
  return (unsigned short)(r >> 16);
}

static __device__ __forceinline__ void gload_lds16(const unsigned short* g, unsigned short* l) {
  __builtin_amdgcn_global_load_lds(
      (const __attribute__((address_space(1))) unsigned int*)g,
      (__attribute__((address_space(3))) unsigned int*)l, 16, 0, 0);
}

// ---------------- fp32 -> bf16 cast ----------------
__global__ void cvt_kernel(const float* __restrict__ in, unsigned short* __restrict__ out, int n4) {
  int idx = blockIdx.x * blockDim.x + threadIdx.x;
  int stride = gridDim.x * blockDim.x;
  for (int i = idx; i < n4; i += stride) {
    float4 v = ((const float4*)in)[i];
    u16x4 o;
    o.x = f2bf(v.x); o.y = f2bf(v.y); o.z = f2bf(v.z); o.w = f2bf(v.w);
    ((u16x4*)out)[i] = o;
  }
}

// ---------------- GEMM: C[M,N] = A[M,K] @ W[N,K]^T + bias ----------------
// MODE 0: write bf16 [B,H,S,D]   (Q, K)
// MODE 1: write bf16 [B,H,D,S]   (V transposed)
// MODE 2: write f32 row-major    (final output)
template<int MODE>
__global__ __launch_bounds__(256, 2)
void gemm_bt(const unsigned short* __restrict__ A,
             const unsigned short* __restrict__ W,
             const float* __restrict__ bias,
             void* __restrict__ out,
             int M, int N, int K) {
  __shared__ unsigned short A_lds[128 * 64];
  __shared__ unsigned short B_lds[128 * 64];
  const int tid = threadIdx.x;
  const int w = tid >> 6, l = tid & 63;
  const int wr = w >> 1, wc = w & 1;
  const int r16 = l & 15, g = l >> 4;
  const int nbj = N >> 7;
  const int bi = blockIdx.x / nbj, bj = blockIdx.x % nbj;
  const int row0 = bi * 128, col0 = bj * 128;

  f32x4 acc[4][4];
#pragma unroll
  for (int i = 0; i < 4; ++i)
#pragma unroll
    for (int j = 0; j < 4; ++j) acc[i][j] = (f32x4){0.f, 0.f, 0.f, 0.f};

  const int srow = tid >> 3;          // 0..31 within an issue
  const int scol = (tid & 7) * 8;     // element col (8 bf16 = 16 B)
  const int kt_steps = K >> 6;

  for (int kt = 0; kt < kt_steps; ++kt) {
    const int k0 = kt * 64;
    // stage A tile [128][64] and B tile [128][64], linear LDS (global_load_lds)
#pragma unroll
    for (int j = 0; j < 4; ++j)
      gload_lds16(A + (size_t)(row0 + j * 32 + srow) * K + k0 + scol,
                  A_lds + j * 2048 + w * 512);
#pragma unroll
    for (int j = 0; j < 4; ++j)
      gload_lds16(W + (size_t)(col0 + j * 32 + srow) * K + k0 + scol,
                  B_lds + j * 2048 + w * 512);
    __syncthreads();
#pragma unroll
    for (int ks = 0; ks < 2; ++ks) {
      bf16x8 af[4], bfr[4];
#pragma unroll
      for (int mf = 0; mf < 4; ++mf)
        af[mf] = *(const bf16x8*)(A_lds + (wr * 64 + mf * 16 + r16) * 64 + ks * 32 + g * 8);
#pragma unroll
      for (int nf = 0; nf < 4; ++nf)
        bfr[nf] = *(const bf16x8*)(B_lds + (wc * 64 + nf * 16 + r16) * 64 + ks * 32 + g * 8);
#pragma unroll
      for (int mf = 0; mf < 4; ++mf)
#pragma unroll
        for (int nf = 0; nf < 4; ++nf)
          acc[mf][nf] = __builtin_amdgcn_mfma_f32_16x16x32_bf16(af[mf], bfr[nf], acc[mf][nf], 0, 0, 0);
    }
    __syncthreads();
  }

  // epilogue: bias + store. C/D layout: col = lane&15, row = (lane>>4)*4 + reg
#pragma unroll
  for (int mf = 0; mf < 4; ++mf) {
    const int irow = row0 + wr * 64 + mf * 16 + g * 4;
#pragma unroll
    for (int nf = 0; nf < 4; ++nf) {
      const int jcol = col0 + wc * 64 + nf * 16 + r16;
      const float bv = bias[jcol];
#pragma unroll
      for (int r = 0; r < 4; ++r) {
        const float val = acc[mf][nf][r] + bv;
        const int i = irow + r;
        if (MODE == 2) {
          ((float*)out)[(size_t)i * N + jcol] = val;
        } else {
          const int b = i >> 11, s = i & 2047, hh = jcol >> 6, d = jcol & 63;
          size_t off;
          if (MODE == 0) off = (((size_t)(b * NHEADS + hh)) * SEQ + s) * HDIM + d;
          else           off = (((size_t)(b * NHEADS + hh)) * HDIM + d) * SEQ + s;
          ((unsigned short*)out)[off] = f2bf(val);
        }
      }
    }
  }
}

// ---------------- causal flash attention ----------------
// Q,K: [B,H,S,D] bf16; Vt: [B,H,D,S] bf16; O: [B,S,H*D] bf16
__global__ __launch_bounds__(256, 2)
void attn_kernel(const unsigned short* __restrict__ Q,
                 const unsigned short* __restrict__ K,
                 const unsigned short* __restrict__ Vt,
                 unsigned short* __restrict__ O) {
  __shared__ unsigned short K_lds[64 * 72];   // [key][d], padded rows
  __shared__ unsigned short V_lds[64 * 72];   // [d][key], padded rows
  __shared__ unsigned short P_lds[4][32 * 72];
  const int tid = threadIdx.x;
  const int w = tid >> 6, l = tid & 63;
  const int r16 = l & 15, g = l >> 4;
  const int qb = blockIdx.x & 15;
  const int bh = blockIdx.x >> 4;
  const unsigned short* Qh = Q + (size_t)bh * SEQ * HDIM;
  const unsigned short* Kh = K + (size_t)bh * SEQ * HDIM;
  const unsigned short* Vh = Vt + (size_t)bh * HDIM * SEQ;

  const int wrow0 = qb * 128 + w * 32;
  bf16x8 qf[2][2];
#pragma unroll
  for (int mf = 0; mf < 2; ++mf)
#pragma unroll
    for (int ks = 0; ks < 2; ++ks)
      qf[mf][ks] = *(const bf16x8*)(Qh + (size_t)(wrow0 + mf * 16 + r16) * HDIM + ks * 32 + g * 8);

  f32x4 oacc[2][4];
  float m_run[2][4], l_run[2][4];
#pragma unroll
  for (int mf = 0; mf < 2; ++mf) {
#pragma unroll
    for (int df = 0; df < 4; ++df) oacc[mf][df] = (f32x4){0.f, 0.f, 0.f, 0.f};
#pragma unroll
    for (int r = 0; r < 4; ++r) { m_run[mf][r] = -3.0e38f; l_run[mf][r] = 0.f; }
  }

  const int srow = tid >> 3;
  const int scol = (tid & 7) * 8;
  const int n_tiles = 2 * qb + 2;
  const int wrow_max = wrow0 + 31;
  const float k1 = ATT_SCALE * LOG2E;

  for (int t = 0; t < n_tiles; ++t) {
    bf16x8 kreg[2], vreg[2];
#pragma unroll
    for (int j = 0; j < 2; ++j) {
      const int rr = j * 32 + srow;
      kreg[j] = *(const bf16x8*)(Kh + (size_t)(t * 64 + rr) * HDIM + scol);
      vreg[j] = *(const bf16x8*)(Vh + (size_t)rr * SEQ + t * 64 + scol);
    }
    __syncthreads();
#pragma unroll
    for (int j = 0; j < 2; ++j) {
      const int rr = j * 32 + srow;
      *(bf16x8*)(K_lds + rr * 72 + scol) = kreg[j];
      *(bf16x8*)(V_lds + rr * 72 + scol) = vreg[j];
    }
    __syncthreads();
    if (t * 64 > wrow_max) continue;  // tile fully masked for this wave (uniform)

    // scores S = Q K^T (per wave: 32 rows x 64 keys)
    f32x4 sf[2][4];
#pragma unroll
    for (int mf = 0; mf < 2; ++mf)
#pragma unroll
      for (int nf = 0; nf < 4; ++nf) sf[mf][nf] = (f32x4){0.f, 0.f, 0.f, 0.f};
#pragma unroll
    for (int ks = 0; ks < 2; ++ks) {
      bf16x8 kf[4];
#pragma unroll
      for (int nf = 0; nf < 4; ++nf)
        kf[nf] = *(const bf16x8*)(K_lds + (nf * 16 + r16) * 72 + ks * 32 + g * 8);
#pragma unroll
      for (int mf = 0; mf < 2; ++mf)
#pragma unroll
        for (int nf = 0; nf < 4; ++nf)
          sf[mf][nf] = __builtin_amdgcn_mfma_f32_16x16x32_bf16(qf[mf][ks], kf[nf], sf[mf][nf], 0, 0, 0);
    }

#pragma unroll
    for (int mf = 0; mf < 2; ++mf) {
      float mnew[4];
#pragma unroll
      for (int r = 0; r < 4; ++r) mnew[r] = -3.0e38f;
#pragma unroll
      for (int nf = 0; nf < 4; ++nf) {
        const int kcol = t * 64 + nf * 16 + r16;
#pragma unroll
        for (int r = 0; r < 4; ++r) {
          const int qrow = wrow0 + mf * 16 + g * 4 + r;
          float e = sf[mf][nf][r] * k1;
          if (kcol > qrow) e = -3.0e38f;
          sf[mf][nf][r] = e;
          mnew[r] = fmaxf(mnew[r], e);
        }
      }
#pragma unroll
      for (int r = 0; r < 4; ++r) {
        float v = mnew[r];
        v = fmaxf(v, __shfl_xor(v, 1));
        v = fmaxf(v, __shfl_xor(v, 2));
        v = fmaxf(v, __shfl_xor(v, 4));
        v = fmaxf(v, __shfl_xor(v, 8));
        const float mn = fmaxf(m_run[mf][r], v);
        const float alpha = exp2f(m_run[mf][r] - mn);
        m_run[mf][r] = mn;
        l_run[mf][r] *= alpha;
#pragma unroll
        for (int df = 0; df < 4; ++df) oacc[mf][df][r] *= alpha;
        mnew[r] = mn;
      }
#pragma unroll
      for (int r = 0; r < 4; ++r) {
        float lsum = 0.f;
#pragma unroll
        for (int nf = 0; nf < 4; ++nf) {
          const float p = exp2f(sf[mf][nf][r] - mnew[r]);
          lsum += p;
          P_lds[w][(mf * 16 + g * 4 + r) * 72 + nf * 16 + r16] = f2bf(p);
        }
        lsum += __shfl_xor(lsum, 1);
        lsum += __shfl_xor(lsum, 2);
        lsum += __shfl_xor(lsum, 4);
        lsum += __shfl_xor(lsum, 8);
        l_run[mf][r] += lsum;
      }
    }

    // O += P @ V  (P from per-wave LDS, V from [d][key] LDS)
#pragma unroll
    for (int kks = 0; kks < 2; ++kks) {
      bf16x8 pf[2], vf[4];
#pragma unroll
      for (int mf = 0; mf < 2; ++mf)
        pf[mf] = *(const bf16x8*)(&P_lds[w][(mf * 16 + r16) * 72 + kks * 32 + g * 8]);
#pragma unroll
      for (int df = 0; df < 4; ++df)
        vf[df] = *(const bf16x8*)(V_lds + (df * 16 + r16) * 72 + kks * 32 + g * 8);
#pragma unroll
      for (int mf = 0; mf < 2; ++mf)
#pragma unroll
        for (int df = 0; df < 4; ++df)
          oacc[mf][df] = __builtin_amdgcn_mfma_f32_16x16x32_bf16(pf[mf], vf[df], oacc[mf][df], 0, 0, 0);
    }
  }

  const int bq = bh >> 5, hh = bh & 31;
#pragma unroll
  for (int mf = 0; mf < 2; ++mf)
#pragma unroll
    for (int r = 0; r < 4; ++r) {
      const int s = wrow0 + mf * 16 + g * 4 + r;
      const float inv = 1.0f / l_run[mf][r];
#pragma unroll
      for (int df = 0; df < 4; ++df) {
        const int d = df * 16 + r16;
        O[((size_t)(bq * SEQ + s)) * EMBED + hh * HDIM + d] = f2bf(oacc[mf][df][r] * inv);
      }
    }
}

extern "C" void kernel_launch(void* const* d_in, const int* in_sizes, int n_in,
                              void* d_out, int out_size, void* d_ws, size_t ws_size,
                              hipStream_t stream) {
  const float* h  = (const float*)d_in[0];
  const float* Wq = (const float*)d_in[1];
  const float* bq = (const float*)d_in[2];
  const float* Wk = (const float*)d_in[3];
  const float* bk = (const float*)d_in[4];
  const float* Wv = (const float*)d_in[5];
  const float* bv = (const float*)d_in[6];
  const float* Wo = (const float*)d_in[7];
  const float* bo = (const float*)d_in[8];

  if (ws_size < (size_t)117440512) return;  // need ~112 MB scratch

  unsigned short* ws = (unsigned short*)d_ws;
  unsigned short* hb = ws;                    // [4096,2048] bf16
  unsigned short* wqb = ws + 8388608;         // [2048,2048]
  unsigned short* wkb = ws + 12582912;
  unsigned short* wvb = ws + 16777216;
  unsigned short* wob = ws + 20971520;
  unsigned short* Qw  = ws + 25165824;        // [B,H,S,D]
  unsigned short* Kw  = ws + 33554432;        // [B,H,S,D]
  unsigned short* Vw  = ws + 41943040;        // [B,H,D,S]
  unsigned short* Ow  = ws + 50331648;        // [B,S,E]

  cvt_kernel<<<1024, 256, 0, stream>>>(h,  hb,  8388608 / 4);
  cvt_kernel<<<512, 256, 0, stream>>>(Wq, wqb, 4194304 / 4);
  cvt_kernel<<<512, 256, 0, stream>>>(Wk, wkb, 4194304 / 4);
  cvt_kernel<<<512, 256, 0, stream>>>(Wv, wvb, 4194304 / 4);
  cvt_kernel<<<512, 256, 0, stream>>>(Wo, wob, 4194304 / 4);

  gemm_bt<0><<<512, 256, 0, stream>>>(hb, wqb, bq, Qw, 4096, 2048, 2048);
  gemm_bt<0><<<512, 256, 0, stream>>>(hb, wkb, bk, Kw, 4096, 2048, 2048);
  gemm_bt<1><<<512, 256, 0, stream>>>(hb, wvb, bv, Vw, 4096, 2048, 2048);

  attn_kernel<<<1024, 256, 0, stream>>>(Qw, Kw, Vw, Ow);

  gemm_bt<2><<<512, 256, 0, stream>>>(Ow, wob, bo, d_out, 4096, 2048, 2048);
}

// Round 2
// 359.021 us; speedup vs baseline: 1.3439x; 1.3439x over previous
//
#include <hip/hip_runtime.h>
#include <hip/hip_bf16.h>
#include <stdint.h>

#define EMBED 2048
#define NHEADS 32
#define HDIM 64
#define BATCH 2
#define SEQ 2048
#define ATT_SCALE 0.125f
#define LOG2E 1.4426950408889634f

typedef __attribute__((ext_vector_type(8))) short bf16x8;
typedef __attribute__((ext_vector_type(4))) float f32x4;
typedef __attribute__((ext_vector_type(4))) unsigned short u16x4;

static __device__ __forceinline__ unsigned short f2bf(float f) {
  union { float f; uint32_t u; } v; v.f = f;
  uint32_t r = v.u + 0x7fffu + ((v.u >> 16) & 1u);
  return (unsigned short)(r >> 16);
}

static __device__ __forceinline__ void gload_lds16(const unsigned short* g, unsigned short* l) {
  __builtin_amdgcn_global_load_lds(
      (const __attribute__((address_space(1))) unsigned int*)g,
      (__attribute__((address_space(3))) unsigned int*)l, 16, 0, 0);
}

// ---------------- fp32 -> bf16 cast ----------------
__global__ void cvt_kernel(const float* __restrict__ in, unsigned short* __restrict__ out, int n4) {
  int idx = blockIdx.x * blockDim.x + threadIdx.x;
  int stride = gridDim.x * blockDim.x;
  for (int i = idx; i < n4; i += stride) {
    float4 v = ((const float4*)in)[i];
    u16x4 o;
    o.x = f2bf(v.x); o.y = f2bf(v.y); o.z = f2bf(v.z); o.w = f2bf(v.w);
    ((u16x4*)out)[i] = o;
  }
}

// ---------------- GEMM: C[M,N] = (A[M,K] @ W[N,K]^T + bias) * oscale ----------------
// MODE 0: write bf16 [B,H,S,D]   (Q, K)
// MODE 1: write bf16 [B,H,D,S]   (V transposed)
// MODE 2: write f32 row-major    (final output)
template<int MODE>
__global__ __launch_bounds__(256, 2)
void gemm_bt(const unsigned short* __restrict__ A,
             const unsigned short* __restrict__ W,
             const float* __restrict__ bias,
             void* __restrict__ out,
             int M, int N, int K, float oscale) {
  __shared__ unsigned short A_lds[128 * 64];
  __shared__ unsigned short B_lds[128 * 64];
  const int tid = threadIdx.x;
  const int w = tid >> 6, l = tid & 63;
  const int wr = w >> 1, wc = w & 1;
  const int r16 = l & 15, g = l >> 4;
  const int nbj = N >> 7;
  const int bi = blockIdx.x / nbj, bj = blockIdx.x % nbj;
  const int row0 = bi * 128, col0 = bj * 128;

  f32x4 acc[4][4];
#pragma unroll
  for (int i = 0; i < 4; ++i)
#pragma unroll
    for (int j = 0; j < 4; ++j) acc[i][j] = (f32x4){0.f, 0.f, 0.f, 0.f};

  const int srow = tid >> 3;          // 0..31 within an issue
  const int scol = (tid & 7) * 8;     // element col (8 bf16 = 16 B)
  const int kt_steps = K >> 6;

  for (int kt = 0; kt < kt_steps; ++kt) {
    const int k0 = kt * 64;
#pragma unroll
    for (int j = 0; j < 4; ++j)
      gload_lds16(A + (size_t)(row0 + j * 32 + srow) * K + k0 + scol,
                  A_lds + j * 2048 + w * 512);
#pragma unroll
    for (int j = 0; j < 4; ++j)
      gload_lds16(W + (size_t)(col0 + j * 32 + srow) * K + k0 + scol,
                  B_lds + j * 2048 + w * 512);
    __syncthreads();
#pragma unroll
    for (int ks = 0; ks < 2; ++ks) {
      bf16x8 af[4], bfr[4];
#pragma unroll
      for (int mf = 0; mf < 4; ++mf)
        af[mf] = *(const bf16x8*)(A_lds + (wr * 64 + mf * 16 + r16) * 64 + ks * 32 + g * 8);
#pragma unroll
      for (int nf = 0; nf < 4; ++nf)
        bfr[nf] = *(const bf16x8*)(B_lds + (wc * 64 + nf * 16 + r16) * 64 + ks * 32 + g * 8);
#pragma unroll
      for (int mf = 0; mf < 4; ++mf)
#pragma unroll
        for (int nf = 0; nf < 4; ++nf)
          acc[mf][nf] = __builtin_amdgcn_mfma_f32_16x16x32_bf16(af[mf], bfr[nf], acc[mf][nf], 0, 0, 0);
    }
    __syncthreads();
  }

  // epilogue: bias + scale + store. C/D layout: col = lane&15, row = (lane>>4)*4 + reg
#pragma unroll
  for (int mf = 0; mf < 4; ++mf) {
    const int irow = row0 + wr * 64 + mf * 16 + g * 4;
#pragma unroll
    for (int nf = 0; nf < 4; ++nf) {
      const int jcol = col0 + wc * 64 + nf * 16 + r16;
      const float bv = bias[jcol];
#pragma unroll
      for (int r = 0; r < 4; ++r) {
        const float val = (acc[mf][nf][r] + bv) * oscale;
        const int i = irow + r;
        if (MODE == 2) {
          ((float*)out)[(size_t)i * N + jcol] = val;
        } else {
          const int b = i >> 11, s = i & 2047, hh = jcol >> 6, d = jcol & 63;
          size_t off;
          if (MODE == 0) off = (((size_t)(b * NHEADS + hh)) * SEQ + s) * HDIM + d;
          else           off = (((size_t)(b * NHEADS + hh)) * HDIM + d) * SEQ + s;
          ((unsigned short*)out)[off] = f2bf(val);
        }
      }
    }
  }
}

// ---------------- causal flash attention ----------------
// Q (pre-scaled by ATT_SCALE*LOG2E), K: [B,H,S,D] bf16; Vt: [B,H,D,S] bf16; O: [B,S,H*D] bf16
// Block = 4 waves, handles q-tiles {pair, 15-pair} of one (b,h) -> uniform 34 tile-units/block.
__global__ __launch_bounds__(256, 2)
void attn_kernel(const unsigned short* __restrict__ Q,
                 const unsigned short* __restrict__ K,
                 const unsigned short* __restrict__ Vt,
                 unsigned short* __restrict__ O) {
  __shared__ unsigned short K_lds[2][64 * 72];
  __shared__ unsigned short V_lds[2][64 * 72];
  __shared__ unsigned short P_lds[4][32 * 72];
  const int tid = threadIdx.x;
  const int w = tid >> 6, l = tid & 63;
  const int r16 = l & 15, g = l >> 4;
  // XCD swizzle: 512 blocks, dispatch i -> XCD i%8; give each XCD 8 complete bh
  const int bid = ((blockIdx.x & 7) << 6) | (blockIdx.x >> 3);
  const int pair = bid & 7;
  const int bh = bid >> 3;
  const unsigned short* Qh = Q + (size_t)bh * SEQ * HDIM;
  const unsigned short* Kh = K + (size_t)bh * SEQ * HDIM;
  const unsigned short* Vh = Vt + (size_t)bh * HDIM * SEQ;
  const int bq = bh >> 5, hh = bh & 31;
  const int srow = tid >> 3;
  const int scol = (tid & 7) * 8;

  for (int half = 0; half < 2; ++half) {
    const int qt = half ? (15 - pair) : pair;
    const int wrow0 = qt * 128 + w * 32;
    const int wrow_max = wrow0 + 31;
    const int n_tiles = 2 * qt + 2;

    bf16x8 qf[2][2];
#pragma unroll
    for (int mf = 0; mf < 2; ++mf)
#pragma unroll
      for (int ks = 0; ks < 2; ++ks)
        qf[mf][ks] = *(const bf16x8*)(Qh + (size_t)(wrow0 + mf * 16 + r16) * HDIM + ks * 32 + g * 8);

    f32x4 oacc[2][4];
    float m_run[2][4], l_run[2][4];
#pragma unroll
    for (int mf = 0; mf < 2; ++mf) {
#pragma unroll
      for (int df = 0; df < 4; ++df) oacc[mf][df] = (f32x4){0.f, 0.f, 0.f, 0.f};
#pragma unroll
      for (int r = 0; r < 4; ++r) { m_run[mf][r] = -3.0e38f; l_run[mf][r] = 0.f; }
    }

    // prologue: stage tile 0 into buffer 0
    bf16x8 kreg[2], vreg[2];
#pragma unroll
    for (int j = 0; j < 2; ++j) {
      const int rr = j * 32 + srow;
      kreg[j] = *(const bf16x8*)(Kh + (size_t)rr * HDIM + scol);
      vreg[j] = *(const bf16x8*)(Vh + (size_t)rr * SEQ + scol);
    }
    __syncthreads();  // protect buf0 against previous half's readers
#pragma unroll
    for (int j = 0; j < 2; ++j) {
      const int rr = j * 32 + srow;
      *(bf16x8*)(K_lds[0] + rr * 72 + scol) = kreg[j];
      *(bf16x8*)(V_lds[0] + rr * 72 + scol) = vreg[j];
    }

    for (int t = 0; t < n_tiles; ++t) {
      const int cur = t & 1;
      const bool not_last = (t + 1 < n_tiles);
      if (not_last) {  // issue next-tile global loads; latency hides under compute
#pragma unroll
        for (int j = 0; j < 2; ++j) {
          const int rr = j * 32 + srow;
          kreg[j] = *(const bf16x8*)(Kh + (size_t)((t + 1) * 64 + rr) * HDIM + scol);
          vreg[j] = *(const bf16x8*)(Vh + (size_t)rr * SEQ + (t + 1) * 64 + scol);
        }
      }
      __syncthreads();  // buf[cur] writes visible; prev readers of buf[cur^1] done

      if (t * 64 <= wrow_max) {
        // scores S = Q K^T (per wave: 32 rows x 64 keys), exp2 domain (Q pre-scaled)
        f32x4 sf[2][4];
#pragma unroll
        for (int mf = 0; mf < 2; ++mf)
#pragma unroll
          for (int nf = 0; nf < 4; ++nf) sf[mf][nf] = (f32x4){0.f, 0.f, 0.f, 0.f};
        __builtin_amdgcn_s_setprio(1);
#pragma unroll
        for (int ks = 0; ks < 2; ++ks) {
          bf16x8 kf[4];
#pragma unroll
          for (int nf = 0; nf < 4; ++nf)
            kf[nf] = *(const bf16x8*)(K_lds[cur] + (nf * 16 + r16) * 72 + ks * 32 + g * 8);
#pragma unroll
          for (int mf = 0; mf < 2; ++mf)
#pragma unroll
            for (int nf = 0; nf < 4; ++nf)
              sf[mf][nf] = __builtin_amdgcn_mfma_f32_16x16x32_bf16(qf[mf][ks], kf[nf], sf[mf][nf], 0, 0, 0);
        }
        __builtin_amdgcn_s_setprio(0);

        const bool need_mask = (t * 64 + 63 > wrow0);  // wave-uniform
#pragma unroll
        for (int mf = 0; mf < 2; ++mf) {
          float mnew[4];
#pragma unroll
          for (int r = 0; r < 4; ++r) mnew[r] = -3.0e38f;
          if (need_mask) {
#pragma unroll
            for (int nf = 0; nf < 4; ++nf) {
              const int kcol = t * 64 + nf * 16 + r16;
#pragma unroll
              for (int r = 0; r < 4; ++r) {
                const int qrow = wrow0 + mf * 16 + g * 4 + r;
                float e = sf[mf][nf][r];
                if (kcol > qrow) e = -3.0e38f;
                sf[mf][nf][r] = e;
                mnew[r] = fmaxf(mnew[r], e);
              }
            }
          } else {
#pragma unroll
            for (int nf = 0; nf < 4; ++nf)
#pragma unroll
              for (int r = 0; r < 4; ++r) mnew[r] = fmaxf(mnew[r], sf[mf][nf][r]);
          }
#pragma unroll
          for (int r = 0; r < 4; ++r) {
            float v = mnew[r];
            v = fmaxf(v, __shfl_xor(v, 1));
            v = fmaxf(v, __shfl_xor(v, 2));
            v = fmaxf(v, __shfl_xor(v, 4));
            v = fmaxf(v, __shfl_xor(v, 8));
            const float mn = fmaxf(m_run[mf][r], v);
            const float alpha = exp2f(m_run[mf][r] - mn);
            m_run[mf][r] = mn;
            l_run[mf][r] *= alpha;
#pragma unroll
            for (int df = 0; df < 4; ++df) oacc[mf][df][r] *= alpha;
            mnew[r] = mn;
          }
#pragma unroll
          for (int r = 0; r < 4; ++r) {
            float lsum = 0.f;
#pragma unroll
            for (int nf = 0; nf < 4; ++nf) {
              const float p = exp2f(sf[mf][nf][r] - mnew[r]);
              lsum += p;
              P_lds[w][(mf * 16 + g * 4 + r) * 72 + nf * 16 + r16] = f2bf(p);
            }
            lsum += __shfl_xor(lsum, 1);
            lsum += __shfl_xor(lsum, 2);
            lsum += __shfl_xor(lsum, 4);
            lsum += __shfl_xor(lsum, 8);
            l_run[mf][r] += lsum;
          }
        }

        // O += P @ V  (P per-wave LDS, V from [d][key] LDS)
        __builtin_amdgcn_s_setprio(1);
#pragma unroll
        for (int kks = 0; kks < 2; ++kks) {
          bf16x8 pf[2], vf[4];
#pragma unroll
          for (int mf = 0; mf < 2; ++mf)
            pf[mf] = *(const bf16x8*)(&P_lds[w][(mf * 16 + r16) * 72 + kks * 32 + g * 8]);
#pragma unroll
          for (int df = 0; df < 4; ++df)
            vf[df] = *(const bf16x8*)(V_lds[cur] + (df * 16 + r16) * 72 + kks * 32 + g * 8);
#pragma unroll
          for (int mf = 0; mf < 2; ++mf)
#pragma unroll
            for (int df = 0; df < 4; ++df)
              oacc[mf][df] = __builtin_amdgcn_mfma_f32_16x16x32_bf16(pf[mf], vf[df], oacc[mf][df], 0, 0, 0);
        }
        __builtin_amdgcn_s_setprio(0);
      }

      if (not_last) {  // write next tile into the other buffer
#pragma unroll
        for (int j = 0; j < 2; ++j) {
          const int rr = j * 32 + srow;
          *(bf16x8*)(K_lds[cur ^ 1] + rr * 72 + scol) = kreg[j];
          *(bf16x8*)(V_lds[cur ^ 1] + rr * 72 + scol) = vreg[j];
        }
      }
    }

#pragma unroll
    for (int mf = 0; mf < 2; ++mf)
#pragma unroll
      for (int r = 0; r < 4; ++r) {
        const int s = wrow0 + mf * 16 + g * 4 + r;
        const float inv = 1.0f / l_run[mf][r];
#pragma unroll
        for (int df = 0; df < 4; ++df) {
          const int d = df * 16 + r16;
          O[((size_t)(bq * SEQ + s)) * EMBED + hh * HDIM + d] = f2bf(oacc[mf][df][r] * inv);
        }
      }
  }
}

extern "C" void kernel_launch(void* const* d_in, const int* in_sizes, int n_in,
                              void* d_out, int out_size, void* d_ws, size_t ws_size,
                              hipStream_t stream) {
  const float* h  = (const float*)d_in[0];
  const float* Wq = (const float*)d_in[1];
  const float* bq = (const float*)d_in[2];
  const float* Wk = (const float*)d_in[3];
  const float* bk = (const float*)d_in[4];
  const float* Wv = (const float*)d_in[5];
  const float* bv = (const float*)d_in[6];
  const float* Wo = (const float*)d_in[7];
  const float* bo = (const float*)d_in[8];

  if (ws_size < (size_t)117440512) return;  // need ~112 MB scratch

  unsigned short* ws = (unsigned short*)d_ws;
  unsigned short* hb = ws;                    // [4096,2048] bf16
  unsigned short* wqb = ws + 8388608;         // [2048,2048]
  unsigned short* wkb = ws + 12582912;
  unsigned short* wvb = ws + 16777216;
  unsigned short* wob = ws + 20971520;
  unsigned short* Qw  = ws + 25165824;        // [B,H,S,D] (pre-scaled)
  unsigned short* Kw  = ws + 33554432;        // [B,H,S,D]
  unsigned short* Vw  = ws + 41943040;        // [B,H,D,S]
  unsigned short* Ow  = ws + 50331648;        // [B,S,E]

  cvt_kernel<<<1024, 256, 0, stream>>>(h,  hb,  8388608 / 4);
  cvt_kernel<<<512, 256, 0, stream>>>(Wq, wqb, 4194304 / 4);
  cvt_kernel<<<512, 256, 0, stream>>>(Wk, wkb, 4194304 / 4);
  cvt_kernel<<<512, 256, 0, stream>>>(Wv, wvb, 4194304 / 4);
  cvt_kernel<<<512, 256, 0, stream>>>(Wo, wob, 4194304 / 4);

  const float qscale = ATT_SCALE * LOG2E;
  gemm_bt<0><<<512, 256, 0, stream>>>(hb, wqb, bq, Qw, 4096, 2048, 2048, qscale);
  gemm_bt<0><<<512, 256, 0, stream>>>(hb, wkb, bk, Kw, 4096, 2048, 2048, 1.0f);
  gemm_bt<1><<<512, 256, 0, stream>>>(hb, wvb, bv, Vw, 4096, 2048, 2048, 1.0f);

  attn_kernel<<<512, 256, 0, stream>>>(Qw, Kw, Vw, Ow);

  gemm_bt<2><<<512, 256, 0, stream>>>(Ow, wob, bo, d_out, 4096, 2048, 2048, 1.0f);
}

// Round 3
// 327.652 us; speedup vs baseline: 1.4726x; 1.0957x over previous
//
#include <hip/hip_runtime.h>
#include <hip/hip_bf16.h>
#include <stdint.h>

#define EMBED 2048
#define NHEADS 32
#define HDIM 64
#define BATCH 2
#define SEQ 2048
#define ATT_SCALE 0.125f
#define LOG2E 1.4426950408889634f

typedef __attribute__((ext_vector_type(8))) short bf16x8;
typedef __attribute__((ext_vector_type(4))) float f32x4;
typedef __attribute__((ext_vector_type(4))) unsigned short u16x4;

static __device__ __forceinline__ unsigned short f2bf(float f) {
  union { float f; uint32_t u; } v; v.f = f;
  uint32_t r = v.u + 0x7fffu + ((v.u >> 16) & 1u);
  return (unsigned short)(r >> 16);
}

static __device__ __forceinline__ unsigned short f2bf_trunc(float f) {
  union { float f; uint32_t u; } v; v.f = f;
  return (unsigned short)(v.u >> 16);
}

static __device__ __forceinline__ void gload_lds16(const unsigned short* g, unsigned short* l) {
  __builtin_amdgcn_global_load_lds(
      (const __attribute__((address_space(1))) unsigned int*)g,
      (__attribute__((address_space(3))) unsigned int*)l, 16, 0, 0);
}

// ---------------- fp32 -> bf16 cast, all 5 tensors fused ----------------
// outputs are contiguous in ws: hb | wqb | wkb | wvb | wob
__global__ void cvt_all(const float* __restrict__ h,
                        const float* __restrict__ Wq, const float* __restrict__ Wk,
                        const float* __restrict__ Wv, const float* __restrict__ Wo,
                        unsigned short* __restrict__ out) {
  const int n4 = 6291456;  // total float4 count
  int idx = blockIdx.x * blockDim.x + threadIdx.x;
  int stride = gridDim.x * blockDim.x;
  for (int i = idx; i < n4; i += stride) {
    const float* src; int off;
    if (i < 2097152)      { src = h;  off = i; }
    else if (i < 3145728) { src = Wq; off = i - 2097152; }
    else if (i < 4194304) { src = Wk; off = i - 3145728; }
    else if (i < 5242880) { src = Wv; off = i - 4194304; }
    else                  { src = Wo; off = i - 5242880; }
    float4 v = ((const float4*)src)[off];
    u16x4 o;
    o.x = f2bf(v.x); o.y = f2bf(v.y); o.z = f2bf(v.z); o.w = f2bf(v.w);
    ((u16x4*)out)[i] = o;
  }
}

// ---------------- GEMM: C[M,N] = (A[M,K] @ W[N,K]^T + bias) * oscale ----------------
// MODE 0: write bf16 [B,H,S,D]   (Q, K)
// MODE 1: write bf16 [B,H,D,S]   (V transposed)
// MODE 2: write f32 row-major    (final output)
template<int MODE>
__global__ __launch_bounds__(256, 2)
void gemm_bt(const unsigned short* __restrict__ A,
             const unsigned short* __restrict__ W,
             const float* __restrict__ bias,
             void* __restrict__ out,
             int M, int N, int K, float oscale) {
  __shared__ unsigned short A_lds[128 * 64];
  __shared__ unsigned short B_lds[128 * 64];
  const int tid = threadIdx.x;
  const int w = tid >> 6, l = tid & 63;
  const int wr = w >> 1, wc = w & 1;
  const int r16 = l & 15, g = l >> 4;
  const int nbj = N >> 7;
  const int bi = blockIdx.x / nbj, bj = blockIdx.x % nbj;
  const int row0 = bi * 128, col0 = bj * 128;

  f32x4 acc[4][4];
#pragma unroll
  for (int i = 0; i < 4; ++i)
#pragma unroll
    for (int j = 0; j < 4; ++j) acc[i][j] = (f32x4){0.f, 0.f, 0.f, 0.f};

  const int srow = tid >> 3;          // 0..31 within an issue
  const int scol = (tid & 7) * 8;     // element col (8 bf16 = 16 B)
  const int kt_steps = K >> 6;

  for (int kt = 0; kt < kt_steps; ++kt) {
    const int k0 = kt * 64;
#pragma unroll
    for (int j = 0; j < 4; ++j)
      gload_lds16(A + (size_t)(row0 + j * 32 + srow) * K + k0 + scol,
                  A_lds + j * 2048 + w * 512);
#pragma unroll
    for (int j = 0; j < 4; ++j)
      gload_lds16(W + (size_t)(col0 + j * 32 + srow) * K + k0 + scol,
                  B_lds + j * 2048 + w * 512);
    __syncthreads();
#pragma unroll
    for (int ks = 0; ks < 2; ++ks) {
      bf16x8 af[4], bfr[4];
#pragma unroll
      for (int mf = 0; mf < 4; ++mf)
        af[mf] = *(const bf16x8*)(A_lds + (wr * 64 + mf * 16 + r16) * 64 + ks * 32 + g * 8);
#pragma unroll
      for (int nf = 0; nf < 4; ++nf)
        bfr[nf] = *(const bf16x8*)(B_lds + (wc * 64 + nf * 16 + r16) * 64 + ks * 32 + g * 8);
#pragma unroll
      for (int mf = 0; mf < 4; ++mf)
#pragma unroll
        for (int nf = 0; nf < 4; ++nf)
          acc[mf][nf] = __builtin_amdgcn_mfma_f32_16x16x32_bf16(af[mf], bfr[nf], acc[mf][nf], 0, 0, 0);
    }
    __syncthreads();
  }

  // epilogue: bias + scale + store. C/D layout: col = lane&15, row = (lane>>4)*4 + reg
#pragma unroll
  for (int mf = 0; mf < 4; ++mf) {
    const int irow = row0 + wr * 64 + mf * 16 + g * 4;
#pragma unroll
    for (int nf = 0; nf < 4; ++nf) {
      const int jcol = col0 + wc * 64 + nf * 16 + r16;
      const float bv = bias[jcol];
#pragma unroll
      for (int r = 0; r < 4; ++r) {
        const float val = (acc[mf][nf][r] + bv) * oscale;
        const int i = irow + r;
        if (MODE == 2) {
          ((float*)out)[(size_t)i * N + jcol] = val;
        } else {
          const int b = i >> 11, s = i & 2047, hh = jcol >> 6, d = jcol & 63;
          size_t off;
          if (MODE == 0) off = (((size_t)(b * NHEADS + hh)) * SEQ + s) * HDIM + d;
          else           off = (((size_t)(b * NHEADS + hh)) * HDIM + d) * SEQ + s;
          ((unsigned short*)out)[off] = f2bf(val);
        }
      }
    }
  }
}

// ---------------- causal flash attention ----------------
// Q (pre-scaled by ATT_SCALE*LOG2E), K: [B,H,S,D] bf16; Vt: [B,H,D,S] bf16; O: [B,S,H*D] bf16
// Block = 4 waves, handles q-tiles {pair, 15-pair} of one (b,h) -> uniform 34 tile-units/block.
__global__ __launch_bounds__(256, 2)
void attn_kernel(const unsigned short* __restrict__ Q,
                 const unsigned short* __restrict__ K,
                 const unsigned short* __restrict__ Vt,
                 unsigned short* __restrict__ O) {
  __shared__ unsigned short K_lds[2][64 * 72];
  __shared__ unsigned short V_lds[2][64 * 72];
  __shared__ unsigned short P_lds[4][32 * 72];
  const int tid = threadIdx.x;
  const int w = tid >> 6, l = tid & 63;
  const int r16 = l & 15, g = l >> 4;
  // XCD swizzle: 512 blocks, dispatch i -> XCD i%8; give each XCD 8 complete bh
  const int bid = ((blockIdx.x & 7) << 6) | (blockIdx.x >> 3);
  const int pair = bid & 7;
  const int bh = bid >> 3;
  const unsigned short* Qh = Q + (size_t)bh * SEQ * HDIM;
  const unsigned short* Kh = K + (size_t)bh * SEQ * HDIM;
  const unsigned short* Vh = Vt + (size_t)bh * HDIM * SEQ;
  const int bq = bh >> 5, hh = bh & 31;
  const int srow = tid >> 3;
  const int scol = (tid & 7) * 8;

  bf16x8 ones;
#pragma unroll
  for (int j = 0; j < 8; ++j) ones[j] = (short)0x3F80;  // bf16 1.0

  for (int half = 0; half < 2; ++half) {
    const int qt = half ? (15 - pair) : pair;
    const int wrow0 = qt * 128 + w * 32;
    const int wrow_max = wrow0 + 31;
    const int n_tiles = 2 * qt + 2;

    bf16x8 qf[2][2];
#pragma unroll
    for (int mf = 0; mf < 2; ++mf)
#pragma unroll
      for (int ks = 0; ks < 2; ++ks)
        qf[mf][ks] = *(const bf16x8*)(Qh + (size_t)(wrow0 + mf * 16 + r16) * HDIM + ks * 32 + g * 8);

    f32x4 oacc[2][4];
    f32x4 lacc[2];
    float m_run[2][4];
#pragma unroll
    for (int mf = 0; mf < 2; ++mf) {
#pragma unroll
      for (int df = 0; df < 4; ++df) oacc[mf][df] = (f32x4){0.f, 0.f, 0.f, 0.f};
      lacc[mf] = (f32x4){0.f, 0.f, 0.f, 0.f};
#pragma unroll
      for (int r = 0; r < 4; ++r) m_run[mf][r] = -3.0e38f;
    }

    // prologue: stage tile 0 into buffer 0
    bf16x8 kreg[2], vreg[2];
#pragma unroll
    for (int j = 0; j < 2; ++j) {
      const int rr = j * 32 + srow;
      kreg[j] = *(const bf16x8*)(Kh + (size_t)rr * HDIM + scol);
      vreg[j] = *(const bf16x8*)(Vh + (size_t)rr * SEQ + scol);
    }
    __syncthreads();  // protect buf0 against previous half's readers
#pragma unroll
    for (int j = 0; j < 2; ++j) {
      const int rr = j * 32 + srow;
      *(bf16x8*)(K_lds[0] + rr * 72 + scol) = kreg[j];
      *(bf16x8*)(V_lds[0] + rr * 72 + scol) = vreg[j];
    }

    for (int t = 0; t < n_tiles; ++t) {
      const int cur = t & 1;
      const bool not_last = (t + 1 < n_tiles);
      if (not_last) {  // issue next-tile global loads; latency hides under compute
#pragma unroll
        for (int j = 0; j < 2; ++j) {
          const int rr = j * 32 + srow;
          kreg[j] = *(const bf16x8*)(Kh + (size_t)((t + 1) * 64 + rr) * HDIM + scol);
          vreg[j] = *(const bf16x8*)(Vh + (size_t)rr * SEQ + (t + 1) * 64 + scol);
        }
      }
      __syncthreads();  // buf[cur] writes visible; prev readers of buf[cur^1] done

      if (t * 64 <= wrow_max) {
        // scores S = Q K^T (per wave: 32 rows x 64 keys), exp2 domain (Q pre-scaled)
        f32x4 sf[2][4];
#pragma unroll
        for (int mf = 0; mf < 2; ++mf)
#pragma unroll
          for (int nf = 0; nf < 4; ++nf) sf[mf][nf] = (f32x4){0.f, 0.f, 0.f, 0.f};
        __builtin_amdgcn_s_setprio(1);
#pragma unroll
        for (int ks = 0; ks < 2; ++ks) {
          bf16x8 kf[4];
#pragma unroll
          for (int nf = 0; nf < 4; ++nf)
            kf[nf] = *(const bf16x8*)(K_lds[cur] + (nf * 16 + r16) * 72 + ks * 32 + g * 8);
#pragma unroll
          for (int mf = 0; mf < 2; ++mf)
#pragma unroll
            for (int nf = 0; nf < 4; ++nf)
              sf[mf][nf] = __builtin_amdgcn_mfma_f32_16x16x32_bf16(qf[mf][ks], kf[nf], sf[mf][nf], 0, 0, 0);
        }
        __builtin_amdgcn_s_setprio(0);

        const bool need_mask = (t * 64 + 63 > wrow0);  // wave-uniform
        if (need_mask) {
#pragma unroll
          for (int mf = 0; mf < 2; ++mf)
#pragma unroll
            for (int nf = 0; nf < 4; ++nf) {
              const int kcol = t * 64 + nf * 16 + r16;
#pragma unroll
              for (int r = 0; r < 4; ++r) {
                const int qrow = wrow0 + mf * 16 + g * 4 + r;
                if (kcol > qrow) sf[mf][nf][r] = -3.0e38f;
              }
            }
        }

        // exact defer-rescale: only pay the reduce/rescale when the max grows
        float vmax[2][4];
        int grow = 0;
#pragma unroll
        for (int mf = 0; mf < 2; ++mf)
#pragma unroll
          for (int r = 0; r < 4; ++r) {
            const float v = fmaxf(fmaxf(sf[mf][0][r], sf[mf][1][r]),
                                  fmaxf(sf[mf][2][r], sf[mf][3][r]));
            vmax[mf][r] = v;
            grow |= (v > m_run[mf][r]) ? 1 : 0;
          }
        if (__any(grow)) {
#pragma unroll
          for (int mf = 0; mf < 2; ++mf)
#pragma unroll
            for (int r = 0; r < 4; ++r) {
              float v = vmax[mf][r];
              v = fmaxf(v, __shfl_xor(v, 1));
              v = fmaxf(v, __shfl_xor(v, 2));
              v = fmaxf(v, __shfl_xor(v, 4));
              v = fmaxf(v, __shfl_xor(v, 8));
              const float mn = fmaxf(m_run[mf][r], v);
              const float alpha = exp2f(m_run[mf][r] - mn);
              m_run[mf][r] = mn;
              lacc[mf][r] *= alpha;
#pragma unroll
              for (int df = 0; df < 4; ++df) oacc[mf][df][r] *= alpha;
            }
        }

        // P = exp2(S - m), truncation-rounded to bf16 (bias cancels in l-normalization)
#pragma unroll
        for (int mf = 0; mf < 2; ++mf)
#pragma unroll
          for (int r = 0; r < 4; ++r)
#pragma unroll
            for (int nf = 0; nf < 4; ++nf) {
              const float p = exp2f(sf[mf][nf][r] - m_run[mf][r]);
              P_lds[w][(mf * 16 + g * 4 + r) * 72 + nf * 16 + r16] = f2bf_trunc(p);
            }

        // O += P @ V ; l += P @ 1  (row-sum rides the matrix pipe)
        __builtin_amdgcn_s_setprio(1);
#pragma unroll
        for (int kks = 0; kks < 2; ++kks) {
          bf16x8 pf[2], vf[4];
#pragma unroll
          for (int mf = 0; mf < 2; ++mf)
            pf[mf] = *(const bf16x8*)(&P_lds[w][(mf * 16 + r16) * 72 + kks * 32 + g * 8]);
#pragma unroll
          for (int df = 0; df < 4; ++df)
            vf[df] = *(const bf16x8*)(V_lds[cur] + (df * 16 + r16) * 72 + kks * 32 + g * 8);
#pragma unroll
          for (int mf = 0; mf < 2; ++mf) {
#pragma unroll
            for (int df = 0; df < 4; ++df)
              oacc[mf][df] = __builtin_amdgcn_mfma_f32_16x16x32_bf16(pf[mf], vf[df], oacc[mf][df], 0, 0, 0);
            lacc[mf] = __builtin_amdgcn_mfma_f32_16x16x32_bf16(pf[mf], ones, lacc[mf], 0, 0, 0);
          }
        }
        __builtin_amdgcn_s_setprio(0);
      }

      if (not_last) {  // write next tile into the other buffer
#pragma unroll
        for (int j = 0; j < 2; ++j) {
          const int rr = j * 32 + srow;
          *(bf16x8*)(K_lds[cur ^ 1] + rr * 72 + scol) = kreg[j];
          *(bf16x8*)(V_lds[cur ^ 1] + rr * 72 + scol) = vreg[j];
        }
      }
    }

#pragma unroll
    for (int mf = 0; mf < 2; ++mf)
#pragma unroll
      for (int r = 0; r < 4; ++r) {
        const int s = wrow0 + mf * 16 + g * 4 + r;
        const float inv = 1.0f / lacc[mf][r];
#pragma unroll
        for (int df = 0; df < 4; ++df) {
          const int d = df * 16 + r16;
          O[((size_t)(bq * SEQ + s)) * EMBED + hh * HDIM + d] = f2bf(oacc[mf][df][r] * inv);
        }
      }
  }
}

extern "C" void kernel_launch(void* const* d_in, const int* in_sizes, int n_in,
                              void* d_out, int out_size, void* d_ws, size_t ws_size,
                              hipStream_t stream) {
  const float* h  = (const float*)d_in[0];
  const float* Wq = (const float*)d_in[1];
  const float* bq = (const float*)d_in[2];
  const float* Wk = (const float*)d_in[3];
  const float* bk = (const float*)d_in[4];
  const float* Wv = (const float*)d_in[5];
  const float* bv = (const float*)d_in[6];
  const float* Wo = (const float*)d_in[7];
  const float* bo = (const float*)d_in[8];

  if (ws_size < (size_t)117440512) return;  // need ~112 MB scratch

  unsigned short* ws = (unsigned short*)d_ws;
  unsigned short* hb = ws;                    // [4096,2048] bf16
  unsigned short* wqb = ws + 8388608;         // [2048,2048]
  unsigned short* wkb = ws + 12582912;
  unsigned short* wvb = ws + 16777216;
  unsigned short* wob = ws + 20971520;
  unsigned short* Qw  = ws + 25165824;        // [B,H,S,D] (pre-scaled)
  unsigned short* Kw  = ws + 33554432;        // [B,H,S,D]
  unsigned short* Vw  = ws + 41943040;        // [B,H,D,S]
  unsigned short* Ow  = ws + 50331648;        // [B,S,E]

  cvt_all<<<2048, 256, 0, stream>>>(h, Wq, Wk, Wv, Wo, ws);

  const float qscale = ATT_SCALE * LOG2E;
  gemm_bt<0><<<512, 256, 0, stream>>>(hb, wqb, bq, Qw, 4096, 2048, 2048, qscale);
  gemm_bt<0><<<512, 256, 0, stream>>>(hb, wkb, bk, Kw, 4096, 2048, 2048, 1.0f);
  gemm_bt<1><<<512, 256, 0, stream>>>(hb, wvb, bv, Vw, 4096, 2048, 2048, 1.0f);

  attn_kernel<<<512, 256, 0, stream>>>(Qw, Kw, Vw, Ow);

  gemm_bt<2><<<512, 256, 0, stream>>>(Ow, wob, bo, d_out, 4096, 2048, 2048, 1.0f);
}

// Round 5
// 274.895 us; speedup vs baseline: 1.7552x; 1.1919x over previous
//
#include <hip/hip_runtime.h>
#include <hip/hip_bf16.h>
#include <stdint.h>

#define EMBED 2048
#define NHEADS 32
#define HDIM 64
#define BATCH 2
#define SEQ 2048
#define ATT_SCALE 0.125f
#define LOG2E 1.4426950408889634f

typedef __attribute__((ext_vector_type(8))) short bf16x8;
typedef __attribute__((ext_vector_type(4))) float f32x4;
typedef __attribute__((ext_vector_type(16))) float f32x16;
typedef __attribute__((ext_vector_type(4))) unsigned short u16x4;
typedef __attribute__((ext_vector_type(2))) unsigned int u32x2;

static __device__ __forceinline__ unsigned short f2bf(float f) {
  union { float f; uint32_t u; } v; v.f = f;
  uint32_t r = v.u + 0x7fffu + ((v.u >> 16) & 1u);
  return (unsigned short)(r >> 16);
}

static __device__ __forceinline__ void gload_lds16(const unsigned short* g, unsigned short* l) {
  __builtin_amdgcn_global_load_lds(
      (const __attribute__((address_space(1))) unsigned int*)g,
      (__attribute__((address_space(3))) unsigned int*)l, 16, 0, 0);
}

// ---------------- fp32 -> bf16 cast, all 5 tensors fused ----------------
__global__ void cvt_all(const float* __restrict__ h,
                        const float* __restrict__ Wq, const float* __restrict__ Wk,
                        const float* __restrict__ Wv, const float* __restrict__ Wo,
                        unsigned short* __restrict__ out) {
  const int n4 = 6291456;
  int idx = blockIdx.x * blockDim.x + threadIdx.x;
  int stride = gridDim.x * blockDim.x;
  for (int i = idx; i < n4; i += stride) {
    const float* src; int off;
    if (i < 2097152)      { src = h;  off = i; }
    else if (i < 3145728) { src = Wq; off = i - 2097152; }
    else if (i < 4194304) { src = Wk; off = i - 3145728; }
    else if (i < 5242880) { src = Wv; off = i - 4194304; }
    else                  { src = Wo; off = i - 5242880; }
    float4 v = ((const float4*)src)[off];
    u16x4 o;
    o.x = f2bf(v.x); o.y = f2bf(v.y); o.z = f2bf(v.z); o.w = f2bf(v.w);
    ((u16x4*)out)[i] = o;
  }
}

// ---------------- merged QKV GEMM: [4096,2048] @ [6144,2048]^T ----------------
// col block 0..2047 -> Q (scaled, [B,H,S,D]); 2048..4095 -> K ([B,H,S,D]); 4096..6143 -> V ([B,H,D,S])
__global__ __launch_bounds__(256, 2)
void gemm_qkv(const unsigned short* __restrict__ A,
              const unsigned short* __restrict__ W,
              const float* __restrict__ biasq, const float* __restrict__ biask,
              const float* __restrict__ biasv,
              unsigned short* __restrict__ Qo, unsigned short* __restrict__ Ko,
              unsigned short* __restrict__ Vo, float qscale) {
  __shared__ unsigned short A_lds[128 * 64];
  __shared__ unsigned short B_lds[128 * 64];
  const int tid = threadIdx.x;
  const int w = tid >> 6, l = tid & 63;
  const int wr = w >> 1, wc = w & 1;
  const int r16 = l & 15, g = l >> 4;
  const int bi = blockIdx.x / 48, bj = blockIdx.x % 48;
  const int row0 = bi * 128, col0 = bj * 128;

  f32x4 acc[4][4];
#pragma unroll
  for (int i = 0; i < 4; ++i)
#pragma unroll
    for (int j = 0; j < 4; ++j) acc[i][j] = (f32x4){0.f, 0.f, 0.f, 0.f};

  const int srow = tid >> 3;
  const int scol = (tid & 7) * 8;

  for (int kt = 0; kt < 32; ++kt) {
    const int k0 = kt * 64;
#pragma unroll
    for (int j = 0; j < 4; ++j)
      gload_lds16(A + (size_t)(row0 + j * 32 + srow) * 2048 + k0 + scol,
                  A_lds + j * 2048 + w * 512);
#pragma unroll
    for (int j = 0; j < 4; ++j)
      gload_lds16(W + (size_t)(col0 + j * 32 + srow) * 2048 + k0 + scol,
                  B_lds + j * 2048 + w * 512);
    __syncthreads();
#pragma unroll
    for (int ks = 0; ks < 2; ++ks) {
      bf16x8 af[4], bfr[4];
#pragma unroll
      for (int mf = 0; mf < 4; ++mf)
        af[mf] = *(const bf16x8*)(A_lds + (wr * 64 + mf * 16 + r16) * 64 + ks * 32 + g * 8);
#pragma unroll
      for (int nf = 0; nf < 4; ++nf)
        bfr[nf] = *(const bf16x8*)(B_lds + (wc * 64 + nf * 16 + r16) * 64 + ks * 32 + g * 8);
#pragma unroll
      for (int mf = 0; mf < 4; ++mf)
#pragma unroll
        for (int nf = 0; nf < 4; ++nf)
          acc[mf][nf] = __builtin_amdgcn_mfma_f32_16x16x32_bf16(af[mf], bfr[nf], acc[mf][nf], 0, 0, 0);
    }
    __syncthreads();
  }

  const int which = col0 >> 11;  // 0=Q 1=K 2=V (block-uniform)
  const float* bb = (which == 0) ? biasq : (which == 1) ? biask : biasv;
  const float osc = (which == 0) ? qscale : 1.0f;
  unsigned short* outp = (which == 0) ? Qo : (which == 1) ? Ko : Vo;
#pragma unroll
  for (int mf = 0; mf < 4; ++mf) {
    const int irow = row0 + wr * 64 + mf * 16 + g * 4;
#pragma unroll
    for (int nf = 0; nf < 4; ++nf) {
      const int jcol = col0 + wc * 64 + nf * 16 + r16;
      const int jl = jcol & 2047;
      const int hh = jl >> 6, d = jl & 63;
      const float bval = bb[jl];
#pragma unroll
      for (int r = 0; r < 4; ++r) {
        const float val = (acc[mf][nf][r] + bval) * osc;
        const int i = irow + r;
        const int b = i >> 11, s = i & 2047;
        size_t off;
        if (which < 2) off = (((size_t)(b * NHEADS + hh)) * SEQ + s) * HDIM + d;
        else           off = (((size_t)(b * NHEADS + hh)) * HDIM + d) * SEQ + s;
        outp[off] = f2bf(val);
      }
    }
  }
}

// ---------------- output-proj GEMM: C[M,N] = A[M,K] @ W[N,K]^T + bias (fp32 out) ----------------
__global__ __launch_bounds__(256, 2)
void gemm_out(const unsigned short* __restrict__ A,
              const unsigned short* __restrict__ W,
              const float* __restrict__ bias,
              float* __restrict__ out) {
  __shared__ unsigned short A_lds[128 * 64];
  __shared__ unsigned short B_lds[128 * 64];
  const int tid = threadIdx.x;
  const int w = tid >> 6, l = tid & 63;
  const int wr = w >> 1, wc = w & 1;
  const int r16 = l & 15, g = l >> 4;
  const int bi = blockIdx.x >> 4, bj = blockIdx.x & 15;
  const int row0 = bi * 128, col0 = bj * 128;

  f32x4 acc[4][4];
#pragma unroll
  for (int i = 0; i < 4; ++i)
#pragma unroll
    for (int j = 0; j < 4; ++j) acc[i][j] = (f32x4){0.f, 0.f, 0.f, 0.f};

  const int srow = tid >> 3;
  const int scol = (tid & 7) * 8;

  for (int kt = 0; kt < 32; ++kt) {
    const int k0 = kt * 64;
#pragma unroll
    for (int j = 0; j < 4; ++j)
      gload_lds16(A + (size_t)(row0 + j * 32 + srow) * 2048 + k0 + scol,
                  A_lds + j * 2048 + w * 512);
#pragma unroll
    for (int j = 0; j < 4; ++j)
      gload_lds16(W + (size_t)(col0 + j * 32 + srow) * 2048 + k0 + scol,
                  B_lds + j * 2048 + w * 512);
    __syncthreads();
#pragma unroll
    for (int ks = 0; ks < 2; ++ks) {
      bf16x8 af[4], bfr[4];
#pragma unroll
      for (int mf = 0; mf < 4; ++mf)
        af[mf] = *(const bf16x8*)(A_lds + (wr * 64 + mf * 16 + r16) * 64 + ks * 32 + g * 8);
#pragma unroll
      for (int nf = 0; nf < 4; ++nf)
        bfr[nf] = *(const bf16x8*)(B_lds + (wc * 64 + nf * 16 + r16) * 64 + ks * 32 + g * 8);
#pragma unroll
      for (int mf = 0; mf < 4; ++mf)
#pragma unroll
        for (int nf = 0; nf < 4; ++nf)
          acc[mf][nf] = __builtin_amdgcn_mfma_f32_16x16x32_bf16(af[mf], bfr[nf], acc[mf][nf], 0, 0, 0);
    }
    __syncthreads();
  }

#pragma unroll
  for (int mf = 0; mf < 4; ++mf) {
    const int irow = row0 + wr * 64 + mf * 16 + g * 4;
#pragma unroll
    for (int nf = 0; nf < 4; ++nf) {
      const int jcol = col0 + wc * 64 + nf * 16 + r16;
      const float bval = bias[jcol];
#pragma unroll
      for (int r = 0; r < 4; ++r)
        out[(size_t)(irow + r) * 2048 + jcol] = acc[mf][nf][r] + bval;
    }
  }
}

// ---------------- causal flash attention, swapped 32x32 QK^T, in-register softmax ----------------
// Q (pre-scaled by ATT_SCALE*LOG2E), K: [B,H,S,D] bf16; Vt: [B,H,D,S] bf16; O: [B,S,H*D] bf16
__global__ __launch_bounds__(256, 2)
void attn_kernel(const unsigned short* __restrict__ Q,
                 const unsigned short* __restrict__ K,
                 const unsigned short* __restrict__ Vt,
                 unsigned short* __restrict__ O) {
  __shared__ unsigned short K_lds[2][64 * 72];   // [key][d], pad 72
  __shared__ unsigned short V_lds[2][64 * 72];   // [d][key], pad 72
  __shared__ __align__(16) float abuf[4][32];    // per-wave alpha transfer
  __shared__ __align__(16) float lbuf[4][32];    // per-wave l transfer
  const int tid = threadIdx.x;
  const int w = tid >> 6, l = tid & 63;
  const int q5 = l & 31, hi = l >> 5;
  const int bid = ((blockIdx.x & 7) << 6) | (blockIdx.x >> 3);  // XCD swizzle
  const int pair = bid & 7;
  const int bh = bid >> 3;
  const unsigned short* Qh = Q + (size_t)bh * SEQ * HDIM;
  const unsigned short* Kh = K + (size_t)bh * SEQ * HDIM;
  const unsigned short* Vh = Vt + (size_t)bh * HDIM * SEQ;
  const int bq = bh >> 5, hh = bh & 31;
  const int srow = tid >> 3;
  const int scol = (tid & 7) * 8;

  for (int half = 0; half < 2; ++half) {
    const int qt = half ? (15 - pair) : pair;
    const int wrow0 = qt * 128 + w * 32;
    const int wrow_max = wrow0 + 31;
    const int n_tiles = 2 * qt + 2;
    const int qrow = wrow0 + q5;

    // Q fragments (B-operand of swapped QK): lane holds Q[qrow][d = ks*16 + hi*8 + j]
    bf16x8 qf[4];
#pragma unroll
    for (int ks = 0; ks < 4; ++ks)
      qf[ks] = *(const bf16x8*)(Qh + (size_t)qrow * HDIM + ks * 16 + hi * 8);

    f32x16 oacc[2];
#pragma unroll
    for (int df = 0; df < 2; ++df)
#pragma unroll
      for (int r = 0; r < 16; ++r) oacc[df][r] = 0.f;
    float m_run = -3.0e38f, l_run = 0.f;

    // prologue: stage tile 0 into buffer 0
    bf16x8 kreg[2], vreg[2];
#pragma unroll
    for (int j = 0; j < 2; ++j) {
      const int rr = j * 32 + srow;
      kreg[j] = *(const bf16x8*)(Kh + (size_t)rr * HDIM + scol);
      vreg[j] = *(const bf16x8*)(Vh + (size_t)rr * SEQ + scol);
    }
    __syncthreads();
#pragma unroll
    for (int j = 0; j < 2; ++j) {
      const int rr = j * 32 + srow;
      *(bf16x8*)(K_lds[0] + rr * 72 + scol) = kreg[j];
      *(bf16x8*)(V_lds[0] + rr * 72 + scol) = vreg[j];
    }

    for (int t = 0; t < n_tiles; ++t) {
      const int cur = t & 1;
      const bool not_last = (t + 1 < n_tiles);
      if (not_last) {
#pragma unroll
        for (int j = 0; j < 2; ++j) {
          const int rr = j * 32 + srow;
          kreg[j] = *(const bf16x8*)(Kh + (size_t)((t + 1) * 64 + rr) * HDIM + scol);
          vreg[j] = *(const bf16x8*)(Vh + (size_t)rr * SEQ + (t + 1) * 64 + scol);
        }
      }
      __syncthreads();

      if (t * 64 <= wrow_max) {
        // S^T = K Q^T via mfma(A=K, B=Q): lane holds S[q=q5][key = kf*32 + (r&3)+8*(r>>2)+4*hi]
        f32x16 skf[2];
#pragma unroll
        for (int kf = 0; kf < 2; ++kf)
#pragma unroll
          for (int r = 0; r < 16; ++r) skf[kf][r] = 0.f;
        __builtin_amdgcn_s_setprio(1);
#pragma unroll
        for (int kf = 0; kf < 2; ++kf)
#pragma unroll
          for (int ks = 0; ks < 4; ++ks) {
            bf16x8 ak = *(const bf16x8*)(K_lds[cur] + (kf * 32 + q5) * 72 + ks * 16 + hi * 8);
            skf[kf] = __builtin_amdgcn_mfma_f32_32x32x16_bf16(ak, qf[ks], skf[kf], 0, 0, 0);
          }
        __builtin_amdgcn_s_setprio(0);

        const bool need_mask = (t * 64 + 63 > wrow0);
        if (need_mask) {
#pragma unroll
          for (int kf = 0; kf < 2; ++kf)
#pragma unroll
            for (int r = 0; r < 16; ++r) {
              const int key = t * 64 + kf * 32 + (r & 3) + 8 * (r >> 2) + 4 * hi;
              if (key > qrow) skf[kf][r] = -3.0e38f;
            }
        }

        // full row max: in-lane over 32 + exchange with partner half
        float mx = -3.0e38f;
#pragma unroll
        for (int kf = 0; kf < 2; ++kf)
#pragma unroll
          for (int r = 0; r < 16; ++r) mx = fmaxf(mx, skf[kf][r]);
        mx = fmaxf(mx, __shfl_xor(mx, 32));

        // defer-max (T13, THR=8): rescale only when the max grows materially
        if (__any(mx > m_run + 8.0f)) {
          const float mnew = fmaxf(m_run, mx);
          const float alpha = exp2f(m_run - mnew);
          m_run = mnew;
          l_run *= alpha;
          if (l < 32) abuf[w][l] = alpha;
          f32x4 av[4];
#pragma unroll
          for (int k = 0; k < 4; ++k)
            av[k] = *(const f32x4*)&abuf[w][8 * k + 4 * hi];
#pragma unroll
          for (int df = 0; df < 2; ++df)
#pragma unroll
            for (int r = 0; r < 16; ++r) oacc[df][r] *= av[r >> 2][r & 3];
        }

        // P = exp2(S - m), pack to bf16 pairs in-register (round-half-up; no LDS)
        unsigned int pkA[8], pkB[8];
        float psum = 0.f;
#pragma unroll
        for (int kf = 0; kf < 2; ++kf)
#pragma unroll
          for (int rr = 0; rr < 4; ++rr) {
            unsigned int pb[4];
#pragma unroll
            for (int j = 0; j < 4; ++j) {
              const float p = exp2f(skf[kf][rr * 4 + j] - m_run);
              psum += p;
              union { float f; unsigned int u; } c; c.f = p;
              pb[j] = c.u + 0x8000u;
            }
            pkA[kf * 4 + rr] = __builtin_amdgcn_perm(pb[1], pb[0], 0x07060302);
            pkB[kf * 4 + rr] = __builtin_amdgcn_perm(pb[3], pb[2], 0x07060302);
          }
        psum += __shfl_xor(psum, 32);
        l_run += psum;

        // O += P @ V: build A-fragments via permlane32_swap (T12), B = V from [d][key] LDS
        __builtin_amdgcn_s_setprio(1);
#pragma unroll
        for (int ks = 0; ks < 4; ++ks) {
          u32x2 ra = __builtin_amdgcn_permlane32_swap(pkA[2 * ks], pkA[2 * ks + 1], false, false);
          u32x2 rb = __builtin_amdgcn_permlane32_swap(pkB[2 * ks], pkB[2 * ks + 1], false, false);
          union { unsigned int u[4]; bf16x8 v; } pa;
          pa.u[0] = ra.x; pa.u[1] = rb.x; pa.u[2] = ra.y; pa.u[3] = rb.y;
#pragma unroll
          for (int df = 0; df < 2; ++df) {
            bf16x8 vf = *(const bf16x8*)(V_lds[cur] + (df * 32 + q5) * 72 + ks * 16 + hi * 8);
            oacc[df] = __builtin_amdgcn_mfma_f32_32x32x16_bf16(pa.v, vf, oacc[df], 0, 0, 0);
          }
        }
        __builtin_amdgcn_s_setprio(0);
      }

      if (not_last) {
#pragma unroll
        for (int j = 0; j < 2; ++j) {
          const int rr = j * 32 + srow;
          *(bf16x8*)(K_lds[cur ^ 1] + rr * 72 + scol) = kreg[j];
          *(bf16x8*)(V_lds[cur ^ 1] + rr * 72 + scol) = vreg[j];
        }
      }
    }

    // epilogue: O[s][d] = oacc / l ; oacc layout: d = df*32+q5, s-row = (r&3)+8*(r>>2)+4*hi
    if (l < 32) lbuf[w][l] = l_run;
    f32x4 lv[4];
#pragma unroll
    for (int k = 0; k < 4; ++k)
      lv[k] = *(const f32x4*)&lbuf[w][8 * k + 4 * hi];
#pragma unroll
    for (int df = 0; df < 2; ++df) {
      const int d = df * 32 + q5;
#pragma unroll
      for (int r = 0; r < 16; ++r) {
        const int s = wrow0 + (r & 3) + 8 * (r >> 2) + 4 * hi;
        const float inv = __builtin_amdgcn_rcpf(lv[r >> 2][r & 3]);
        O[((size_t)(bq * SEQ + s)) * EMBED + hh * HDIM + d] = f2bf(oacc[df][r] * inv);
      }
    }
  }
}

extern "C" void kernel_launch(void* const* d_in, const int* in_sizes, int n_in,
                              void* d_out, int out_size, void* d_ws, size_t ws_size,
                              hipStream_t stream) {
  const float* h  = (const float*)d_in[0];
  const float* Wq = (const float*)d_in[1];
  const float* bq = (const float*)d_in[2];
  const float* Wk = (const float*)d_in[3];
  const float* bk = (const float*)d_in[4];
  const float* Wv = (const float*)d_in[5];
  const float* bv = (const float*)d_in[6];
  const float* Wo = (const float*)d_in[7];
  const float* bo = (const float*)d_in[8];

  if (ws_size < (size_t)117440512) return;

  unsigned short* ws = (unsigned short*)d_ws;
  unsigned short* hb = ws;                    // [4096,2048] bf16
  unsigned short* wqb = ws + 8388608;         // [6144,2048] contiguous QKV weights
  unsigned short* wob = ws + 20971520;
  unsigned short* Qw  = ws + 25165824;        // [B,H,S,D] (pre-scaled)
  unsigned short* Kw  = ws + 33554432;        // [B,H,S,D]
  unsigned short* Vw  = ws + 41943040;        // [B,H,D,S]
  unsigned short* Ow  = ws + 50331648;        // [B,S,E]

  cvt_all<<<2048, 256, 0, stream>>>(h, Wq, Wk, Wv, Wo, ws);

  const float qscale = ATT_SCALE * LOG2E;
  gemm_qkv<<<1536, 256, 0, stream>>>(hb, wqb, bq, bk, bv, Qw, Kw, Vw, qscale);

  attn_kernel<<<512, 256, 0, stream>>>(Qw, Kw, Vw, Ow);

  gemm_out<<<512, 256, 0, stream>>>(Ow, wob, bo, (float*)d_out);
}

// Round 6
// 246.022 us; speedup vs baseline: 1.9612x; 1.1174x over previous
//
#include <hip/hip_runtime.h>
#include <hip/hip_bf16.h>
#include <stdint.h>

#define EMBED 2048
#define NHEADS 32
#define HDIM 64
#define BATCH 2
#define SEQ 2048
#define ATT_SCALE 0.125f
#define LOG2E 1.4426950408889634f

typedef __attribute__((ext_vector_type(8))) short bf16x8;
typedef __attribute__((ext_vector_type(4))) float f32x4;
typedef __attribute__((ext_vector_type(16))) float f32x16;
typedef __attribute__((ext_vector_type(4))) unsigned short u16x4;
typedef __attribute__((ext_vector_type(2))) unsigned int u32x2;

static __device__ __forceinline__ unsigned short f2bf(float f) {
  union { float f; uint32_t u; } v; v.f = f;
  uint32_t r = v.u + 0x7fffu + ((v.u >> 16) & 1u);
  return (unsigned short)(r >> 16);
}

static __device__ __forceinline__ void gload_lds16(const unsigned short* g, unsigned short* l) {
  __builtin_amdgcn_global_load_lds(
      (const __attribute__((address_space(1))) unsigned int*)g,
      (__attribute__((address_space(3))) unsigned int*)l, 16, 0, 0);
}

// ---------------- fp32 -> bf16 cast, all 5 tensors fused ----------------
__global__ void cvt_all(const float* __restrict__ h,
                        const float* __restrict__ Wq, const float* __restrict__ Wk,
                        const float* __restrict__ Wv, const float* __restrict__ Wo,
                        unsigned short* __restrict__ out) {
  const int n4 = 6291456;
  int idx = blockIdx.x * blockDim.x + threadIdx.x;
  int stride = gridDim.x * blockDim.x;
  for (int i = idx; i < n4; i += stride) {
    const float* src; int off;
    if (i < 2097152)      { src = h;  off = i; }
    else if (i < 3145728) { src = Wq; off = i - 2097152; }
    else if (i < 4194304) { src = Wk; off = i - 3145728; }
    else if (i < 5242880) { src = Wv; off = i - 4194304; }
    else                  { src = Wo; off = i - 5242880; }
    float4 v = ((const float4*)src)[off];
    u16x4 o;
    o.x = f2bf(v.x); o.y = f2bf(v.y); o.z = f2bf(v.z); o.w = f2bf(v.w);
    ((u16x4*)out)[i] = o;
  }
}

// ---------------- 8-phase pipelined GEMM: C[M,N] = A[M,K] @ W[N,K]^T + bias ----------------
// BM=256, BN=128, BK=64, 512 threads = 8 waves (4M x 2N), wave tile 64x64.
// Phase (mq,nq) order (00)(01)(10)(11); 8 MFMA/phase; staged with counted vmcnt(3).
// LDS XOR-swizzle: LDS[r][u] = G[r][u ^ (r&7)], u = 16B unit.
// MODE 0: QKV fused epilogue (bf16 scatter); MODE 1: fp32 row-major + bias.
template<int MODE, int NBJ>
__global__ __launch_bounds__(512, 2)
void gemm8(const unsigned short* __restrict__ A,
           const unsigned short* __restrict__ W,
           const float* __restrict__ b0, const float* __restrict__ b1,
           const float* __restrict__ b2,
           unsigned short* __restrict__ o0, unsigned short* __restrict__ o1,
           unsigned short* __restrict__ o2,
           float* __restrict__ fo, float qscale) {
  __shared__ unsigned short lds[2][24576];   // per buf: A [256][64] @0, B [128][64] @16384
  const int tid = threadIdx.x;
  const int w = tid >> 6, l = tid & 63;
  const int wm = w >> 1, wn = w & 1;
  const int r16 = l & 15, g = l >> 4;
  // bijective XCD swizzle (grid % 8 == 0)
  const int nblk = 16 * NBJ;
  const int swz = (blockIdx.x & 7) * (nblk >> 3) + (blockIdx.x >> 3);
  const int bi = swz / NBJ, bj = swz % NBJ;
  const int arow0 = bi * 256, bcol0 = bj * 128;

  f32x4 acc[4][4];
#pragma unroll
  for (int i = 0; i < 4; ++i)
#pragma unroll
    for (int j = 0; j < 4; ++j) acc[i][j] = (f32x4){0.f, 0.f, 0.f, 0.f};

  const int lrow = l >> 3;               // 0..7 within a wave's 8-row chunk
  const int gcu = ((l & 7) ^ lrow) * 8;  // pre-swizzled global column (elements)

  // stage A chunk mq of K-tile t into buf: rows {mq*32 + reg*64 + sub*8}, 2 calls
  auto stageA = [&](int buf, int t, int mq, int call) {
    const int m = call * 8 + w;
    const int row0 = mq * 32 + (m >> 2) * 64 + (m & 3) * 8;
    gload_lds16(A + (size_t)(arow0 + row0 + lrow) * 2048 + t * 64 + gcu,
                &lds[buf][row0 * 64]);
  };
  // stage B chunk nq of K-tile t into buf: rows {nq*32 + reg*64 + sub*8}, 1 call
  auto stageB = [&](int buf, int t, int nq) {
    const int row0 = nq * 32 + (w >> 2) * 64 + (w & 3) * 8;
    gload_lds16(W + (size_t)(bcol0 + row0 + lrow) * 2048 + t * 64 + gcu,
                &lds[buf][16384 + row0 * 64]);
  };
  auto ldA = [&](int buf, int mf, int ks) -> bf16x8 {
    const int row = wm * 64 + mf * 16 + r16;
    const int u = (ks * 4 + g) ^ (r16 & 7);
    return *(const bf16x8*)&lds[buf][row * 64 + u * 8];
  };
  auto ldB = [&](int buf, int nf, int ks) -> bf16x8 {
    const int row = wn * 64 + nf * 16 + r16;
    const int u = (ks * 4 + g) ^ (r16 & 7);
    return *(const bf16x8*)&lds[buf][16384 + row * 64 + u * 8];
  };

  // prologue: tile 0 full -> buf0 (6 calls, oldest), tile 1 early chunks -> buf1 (3 calls)
  stageA(0, 0, 0, 0); stageA(0, 0, 0, 1); stageB(0, 0, 0);
  stageA(0, 0, 1, 0); stageA(0, 0, 1, 1); stageB(0, 0, 1);
  stageA(1, 1, 0, 0); stageA(1, 1, 0, 1); stageB(1, 1, 0);
  asm volatile("s_waitcnt vmcnt(3)" ::: "memory");
  __builtin_amdgcn_sched_barrier(0);
  __builtin_amdgcn_s_barrier();

  bf16x8 af[2][2], bf[4][2];

#define MMA_Q(MQ, NQ)                                                          \
  __builtin_amdgcn_s_setprio(1);                                               \
  _Pragma("unroll")                                                            \
  for (int i = 0; i < 2; ++i)                                                  \
    _Pragma("unroll")                                                          \
    for (int j = 0; j < 2; ++j)                                                \
      _Pragma("unroll")                                                        \
      for (int ks = 0; ks < 2; ++ks)                                           \
        acc[(MQ)*2 + i][(NQ)*2 + j] = __builtin_amdgcn_mfma_f32_16x16x32_bf16( \
            af[i][ks], bf[(NQ)*2 + j][ks], acc[(MQ)*2 + i][(NQ)*2 + j], 0, 0, 0); \
  __builtin_amdgcn_s_setprio(0);

  const int nt = 32;  // K=2048 / 64
  for (int c = 0; c < nt; ++c) {
    const int X = c & 1;
    const bool s1 = (c + 1 < nt), s2 = (c + 2 < nt);
    // ---- Phase 0: (m0,n0); stage tile c+1 A-mq1 -> other buf
    af[0][0] = ldA(X, 0, 0); af[0][1] = ldA(X, 0, 1);
    af[1][0] = ldA(X, 1, 0); af[1][1] = ldA(X, 1, 1);
    bf[0][0] = ldB(X, 0, 0); bf[0][1] = ldB(X, 0, 1);
    bf[1][0] = ldB(X, 1, 0); bf[1][1] = ldB(X, 1, 1);
    if (s1) { stageA(X ^ 1, c + 1, 1, 0); stageA(X ^ 1, c + 1, 1, 1); }
    MMA_Q(0, 0);
    __builtin_amdgcn_s_barrier();
    // ---- Phase 1: (m0,n1); stage tile c+1 B-nq1 -> other buf
    bf[2][0] = ldB(X, 2, 0); bf[2][1] = ldB(X, 2, 1);
    bf[3][0] = ldB(X, 3, 0); bf[3][1] = ldB(X, 3, 1);
    if (s1) stageB(X ^ 1, c + 1, 1);
    MMA_Q(0, 1);
    __builtin_amdgcn_s_barrier();
    // ---- Phase 2: (m1,n0); stage tile c+2 A-mq0 -> this buf (rows died after Ph1)
    af[0][0] = ldA(X, 2, 0); af[0][1] = ldA(X, 2, 1);
    af[1][0] = ldA(X, 3, 0); af[1][1] = ldA(X, 3, 1);
    if (s2) { stageA(X, c + 2, 0, 0); stageA(X, c + 2, 0, 1); }
    MMA_Q(1, 0);
    __builtin_amdgcn_s_barrier();
    // ---- Phase 3: (m1,n1); stage tile c+2 B-nq0 -> this buf (rows died after Ph2)
    if (s2) stageB(X, c + 2, 0);
    MMA_Q(1, 1);
    if (s2) asm volatile("s_waitcnt vmcnt(3)" ::: "memory");
    else    asm volatile("s_waitcnt vmcnt(0)" ::: "memory");
    __builtin_amdgcn_sched_barrier(0);
    __builtin_amdgcn_s_barrier();
  }
#undef MMA_Q

  // epilogue
#pragma unroll
  for (int mf = 0; mf < 4; ++mf) {
    const int irow = arow0 + wm * 64 + mf * 16 + g * 4;
#pragma unroll
    for (int nf = 0; nf < 4; ++nf) {
      const int jcol = bcol0 + wn * 64 + nf * 16 + r16;
      if (MODE == 1) {
        const float bval = b0[jcol];
#pragma unroll
        for (int rr = 0; rr < 4; ++rr)
          fo[(size_t)(irow + rr) * 2048 + jcol] = acc[mf][nf][rr] + bval;
      } else {
        const int which = bj >> 4;  // 0=Q 1=K 2=V
        const int jl = jcol & 2047;
        const int hh = jl >> 6, d = jl & 63;
        const float bval = (which == 0) ? b0[jl] : (which == 1) ? b1[jl] : b2[jl];
        const float osc = (which == 0) ? qscale : 1.0f;
        unsigned short* outp = (which == 0) ? o0 : (which == 1) ? o1 : o2;
#pragma unroll
        for (int rr = 0; rr < 4; ++rr) {
          const float val = (acc[mf][nf][rr] + bval) * osc;
          const int i = irow + rr;
          const int b = i >> 11, s = i & 2047;
          size_t off;
          if (which < 2) off = (((size_t)(b * NHEADS + hh)) * SEQ + s) * HDIM + d;
          else           off = (((size_t)(b * NHEADS + hh)) * HDIM + d) * SEQ + s;
          outp[off] = f2bf(val);
        }
      }
    }
  }
}

// ---------------- causal flash attention, swapped 32x32 QK^T, in-register softmax ----------------
// Q (pre-scaled by ATT_SCALE*LOG2E), K: [B,H,S,D] bf16; Vt: [B,H,D,S] bf16; O: [B,S,H*D] bf16
__global__ __launch_bounds__(256, 2)
void attn_kernel(const unsigned short* __restrict__ Q,
                 const unsigned short* __restrict__ K,
                 const unsigned short* __restrict__ Vt,
                 unsigned short* __restrict__ O) {
  __shared__ unsigned short K_lds[2][64 * 72];   // [key][d], pad 72
  __shared__ unsigned short V_lds[2][64 * 72];   // [d][key], pad 72
  __shared__ __align__(16) float abuf[4][32];    // per-wave alpha transfer
  __shared__ __align__(16) float lbuf[4][32];    // per-wave l transfer
  const int tid = threadIdx.x;
  const int w = tid >> 6, l = tid & 63;
  const int q5 = l & 31, hi = l >> 5;
  const int bid = ((blockIdx.x & 7) << 6) | (blockIdx.x >> 3);  // XCD swizzle
  const int pair = bid & 7;
  const int bh = bid >> 3;
  const unsigned short* Qh = Q + (size_t)bh * SEQ * HDIM;
  const unsigned short* Kh = K + (size_t)bh * SEQ * HDIM;
  const unsigned short* Vh = Vt + (size_t)bh * HDIM * SEQ;
  const int bq = bh >> 5, hh = bh & 31;
  const int srow = tid >> 3;
  const int scol = (tid & 7) * 8;

  for (int half = 0; half < 2; ++half) {
    const int qt = half ? (15 - pair) : pair;
    const int wrow0 = qt * 128 + w * 32;
    const int wrow_max = wrow0 + 31;
    const int n_tiles = 2 * qt + 2;
    const int qrow = wrow0 + q5;

    bf16x8 qf[4];
#pragma unroll
    for (int ks = 0; ks < 4; ++ks)
      qf[ks] = *(const bf16x8*)(Qh + (size_t)qrow * HDIM + ks * 16 + hi * 8);

    f32x16 oacc[2];
#pragma unroll
    for (int df = 0; df < 2; ++df)
#pragma unroll
      for (int r = 0; r < 16; ++r) oacc[df][r] = 0.f;
    float m_run = -3.0e38f, l_run = 0.f;

    bf16x8 kreg[2], vreg[2];
#pragma unroll
    for (int j = 0; j < 2; ++j) {
      const int rr = j * 32 + srow;
      kreg[j] = *(const bf16x8*)(Kh + (size_t)rr * HDIM + scol);
      vreg[j] = *(const bf16x8*)(Vh + (size_t)rr * SEQ + scol);
    }
    __syncthreads();
#pragma unroll
    for (int j = 0; j < 2; ++j) {
      const int rr = j * 32 + srow;
      *(bf16x8*)(K_lds[0] + rr * 72 + scol) = kreg[j];
      *(bf16x8*)(V_lds[0] + rr * 72 + scol) = vreg[j];
    }

    for (int t = 0; t < n_tiles; ++t) {
      const int cur = t & 1;
      const bool not_last = (t + 1 < n_tiles);
      if (not_last) {
#pragma unroll
        for (int j = 0; j < 2; ++j) {
          const int rr = j * 32 + srow;
          kreg[j] = *(const bf16x8*)(Kh + (size_t)((t + 1) * 64 + rr) * HDIM + scol);
          vreg[j] = *(const bf16x8*)(Vh + (size_t)rr * SEQ + (t + 1) * 64 + scol);
        }
      }
      __syncthreads();

      if (t * 64 <= wrow_max) {
        f32x16 skf[2];
#pragma unroll
        for (int kf = 0; kf < 2; ++kf)
#pragma unroll
          for (int r = 0; r < 16; ++r) skf[kf][r] = 0.f;
        __builtin_amdgcn_s_setprio(1);
#pragma unroll
        for (int kf = 0; kf < 2; ++kf)
#pragma unroll
          for (int ks = 0; ks < 4; ++ks) {
            bf16x8 ak = *(const bf16x8*)(K_lds[cur] + (kf * 32 + q5) * 72 + ks * 16 + hi * 8);
            skf[kf] = __builtin_amdgcn_mfma_f32_32x32x16_bf16(ak, qf[ks], skf[kf], 0, 0, 0);
          }
        __builtin_amdgcn_s_setprio(0);

        const bool need_mask = (t * 64 + 63 > wrow0);
        if (need_mask) {
#pragma unroll
          for (int kf = 0; kf < 2; ++kf)
#pragma unroll
            for (int r = 0; r < 16; ++r) {
              const int key = t * 64 + kf * 32 + (r & 3) + 8 * (r >> 2) + 4 * hi;
              if (key > qrow) skf[kf][r] = -3.0e38f;
            }
        }

        float mx = -3.0e38f;
#pragma unroll
        for (int kf = 0; kf < 2; ++kf)
#pragma unroll
          for (int r = 0; r < 16; ++r) mx = fmaxf(mx, skf[kf][r]);
        mx = fmaxf(mx, __shfl_xor(mx, 32));

        if (__any(mx > m_run + 8.0f)) {
          const float mnew = fmaxf(m_run, mx);
          const float alpha = exp2f(m_run - mnew);
          m_run = mnew;
          l_run *= alpha;
          if (l < 32) abuf[w][l] = alpha;
          f32x4 av[4];
#pragma unroll
          for (int k = 0; k < 4; ++k)
            av[k] = *(const f32x4*)&abuf[w][8 * k + 4 * hi];
#pragma unroll
          for (int df = 0; df < 2; ++df)
#pragma unroll
            for (int r = 0; r < 16; ++r) oacc[df][r] *= av[r >> 2][r & 3];
        }

        unsigned int pkA[8], pkB[8];
        float psum = 0.f;
#pragma unroll
        for (int kf = 0; kf < 2; ++kf)
#pragma unroll
          for (int rr = 0; rr < 4; ++rr) {
            unsigned int pb[4];
#pragma unroll
            for (int j = 0; j < 4; ++j) {
              const float p = exp2f(skf[kf][rr * 4 + j] - m_run);
              psum += p;
              union { float f; unsigned int u; } c; c.f = p;
              pb[j] = c.u + 0x8000u;
            }
            pkA[kf * 4 + rr] = __builtin_amdgcn_perm(pb[1], pb[0], 0x07060302);
            pkB[kf * 4 + rr] = __builtin_amdgcn_perm(pb[3], pb[2], 0x07060302);
          }
        psum += __shfl_xor(psum, 32);
        l_run += psum;

        __builtin_amdgcn_s_setprio(1);
#pragma unroll
        for (int ks = 0; ks < 4; ++ks) {
          u32x2 ra = __builtin_amdgcn_permlane32_swap(pkA[2 * ks], pkA[2 * ks + 1], false, false);
          u32x2 rb = __builtin_amdgcn_permlane32_swap(pkB[2 * ks], pkB[2 * ks + 1], false, false);
          union { unsigned int u[4]; bf16x8 v; } pa;
          pa.u[0] = ra.x; pa.u[1] = rb.x; pa.u[2] = ra.y; pa.u[3] = rb.y;
#pragma unroll
          for (int df = 0; df < 2; ++df) {
            bf16x8 vf = *(const bf16x8*)(V_lds[cur] + (df * 32 + q5) * 72 + ks * 16 + hi * 8);
            oacc[df] = __builtin_amdgcn_mfma_f32_32x32x16_bf16(pa.v, vf, oacc[df], 0, 0, 0);
          }
        }
        __builtin_amdgcn_s_setprio(0);
      }

      if (not_last) {
#pragma unroll
        for (int j = 0; j < 2; ++j) {
          const int rr = j * 32 + srow;
          *(bf16x8*)(K_lds[cur ^ 1] + rr * 72 + scol) = kreg[j];
          *(bf16x8*)(V_lds[cur ^ 1] + rr * 72 + scol) = vreg[j];
        }
      }
    }

    if (l < 32) lbuf[w][l] = l_run;
    f32x4 lv[4];
#pragma unroll
    for (int k = 0; k < 4; ++k)
      lv[k] = *(const f32x4*)&lbuf[w][8 * k + 4 * hi];
#pragma unroll
    for (int df = 0; df < 2; ++df) {
      const int d = df * 32 + q5;
#pragma unroll
      for (int r = 0; r < 16; ++r) {
        const int s = wrow0 + (r & 3) + 8 * (r >> 2) + 4 * hi;
        const float inv = __builtin_amdgcn_rcpf(lv[r >> 2][r & 3]);
        O[((size_t)(bq * SEQ + s)) * EMBED + hh * HDIM + d] = f2bf(oacc[df][r] * inv);
      }
    }
  }
}

extern "C" void kernel_launch(void* const* d_in, const int* in_sizes, int n_in,
                              void* d_out, int out_size, void* d_ws, size_t ws_size,
                              hipStream_t stream) {
  const float* h  = (const float*)d_in[0];
  const float* Wq = (const float*)d_in[1];
  const float* bq = (const float*)d_in[2];
  const float* Wk = (const float*)d_in[3];
  const float* bk = (const float*)d_in[4];
  const float* Wv = (const float*)d_in[5];
  const float* bv = (const float*)d_in[6];
  const float* Wo = (const float*)d_in[7];
  const float* bo = (const float*)d_in[8];

  if (ws_size < (size_t)117440512) return;

  unsigned short* ws = (unsigned short*)d_ws;
  unsigned short* hb = ws;                    // [4096,2048] bf16
  unsigned short* wqb = ws + 8388608;         // [6144,2048] contiguous QKV weights
  unsigned short* wob = ws + 20971520;
  unsigned short* Qw  = ws + 25165824;        // [B,H,S,D] (pre-scaled)
  unsigned short* Kw  = ws + 33554432;        // [B,H,S,D]
  unsigned short* Vw  = ws + 41943040;        // [B,H,D,S]
  unsigned short* Ow  = ws + 50331648;        // [B,S,E]

  cvt_all<<<2048, 256, 0, stream>>>(h, Wq, Wk, Wv, Wo, ws);

  const float qscale = ATT_SCALE * LOG2E;
  gemm8<0, 48><<<768, 512, 0, stream>>>(hb, wqb, bq, bk, bv, Qw, Kw, Vw, nullptr, qscale);

  attn_kernel<<<512, 256, 0, stream>>>(Qw, Kw, Vw, Ow);

  gemm8<1, 16><<<256, 512, 0, stream>>>(Ow, wob, bo, bo, bo, nullptr, nullptr, nullptr,
                                        (float*)d_out, 1.0f);
}